// Round 4
// baseline (202.253 us; speedup 1.0000x reference)
//
#include <hip/hip_runtime.h>

#define BINS  30
#define NROWS 8192
#define NCOLS 2048
#define COLS_PER_BLK 256                 // grid.x = 8
#define ROWS_PER_BLK 128                 // grid.y = 64
#define YSLICES 64

#define FIXED_SCALE 16384.0f             // 2^14 fixed point for bce
#define CNT_SHIFT   24                   // count bits [24:31], sum in [0:24)
#define SUM_MASK    ((1u << CNT_SHIFT) - 1)

// ws layout (bytes):
//   part : u32[YSLICES][BINS][NCOLS]   (15.7 MB)
//   blockPart: float[8]
//   ctr  : u32 (last-block-done counter)
#define WS_PART  0
#define WS_BPART (YSLICES * BINS * NCOLS * 4)
#define WS_CTR   (WS_BPART + 8 * 4)

// ---------------------------------------------------------------------------
// Kernel A (FROZEN from R3 for attribution): direct column ownership.
// Thread t owns column colBase+t: coalesced dword loads, exclusive plain
// LDS RMW (no atomics, no hot-loop barriers). ~50 us, capped by a ~2.8 TB/s
// delivered-traffic wall (invariant across R0-R3 structures).
// ---------------------------------------------------------------------------
__global__ __launch_bounds__(256, 5) void k_main(
    const float* __restrict__ preds, const int* __restrict__ targets,
    unsigned int* __restrict__ part, unsigned int* __restrict__ ctr)
{
    __shared__ unsigned int H[BINS * COLS_PER_BLK];   // 30720 B
    const int t = threadIdx.x;
    if (blockIdx.x == 0 && blockIdx.y == 0 && t == 0) atomicExch(ctr, 0u);
    #pragma unroll
    for (int i = 0; i < BINS; ++i) H[i * COLS_PER_BLK + t] = 0u;
    __syncthreads();

    const int col = blockIdx.x * COLS_PER_BLK + t;
    const int r0  = blockIdx.y * ROWS_PER_BLK;
    const float* P = preds   + (size_t)r0 * NCOLS + col;
    const int*   T = targets + (size_t)r0 * NCOLS + col;

    // prologue: batch 0 (8 rows) in flight
    float pc[8]; int tc[8];
    #pragma unroll
    for (int r = 0; r < 8; ++r) { pc[r] = P[r * NCOLS]; tc[r] = T[r * NCOLS]; }

    #pragma unroll 1
    for (int batch = 0; batch < ROWS_PER_BLK / 8; ++batch) {
        float pn[8]; int tn[8];
        if (batch < ROWS_PER_BLK / 8 - 1) {
            P += 8 * NCOLS; T += 8 * NCOLS;
            #pragma unroll
            for (int r = 0; r < 8; ++r) { pn[r] = P[r * NCOLS]; tn[r] = T[r * NCOLS]; }
        }
        __builtin_amdgcn_sched_barrier(0);   // prefetch loads may not sink

        #pragma unroll
        for (int r = 0; r < 8; ++r) {
            float p  = pc[r];
            float pp = tc[r] ? -p : p;                    // p'
            float e  = __expf(-fabsf(pp));                // exp(-|p'|)
            float d  = 1.0f + e;
            float r1 = __builtin_amdgcn_rcpf(d);
            float g  = (pp >= 0.0f) ? r1 : e * r1;        // sigmoid(p')
            int   b  = (int)(g * 30.0f);
            b = b > (BINS - 1) ? (BINS - 1) : b;
            float bce = fmaxf(pp, 0.0f) + __logf(d);      // softplus(p')
            unsigned int pk = (1u << CNT_SHIFT)
                | (unsigned int)(bce * FIXED_SCALE + 0.5f);
            H[b * COLS_PER_BLK + t] += pk;                // exclusive, plain RMW
        }
        #pragma unroll
        for (int r = 0; r < 8; ++r) { pc[r] = pn[r]; tc[r] = tn[r]; }
    }
    __syncthreads();

    // flush: straight copy, coalesced
    const size_t outBase = (size_t)blockIdx.y * BINS * NCOLS
                         + (size_t)blockIdx.x * COLS_PER_BLK;
    for (int i = t; i < BINS * COLS_PER_BLK; i += 256)
        part[outBase + (size_t)(i >> 8) * NCOLS + (i & 255)] = H[i];
}

// ---------------------------------------------------------------------------
// Kernel B (R4): FUSED tail — y-slice reduction + per-column contraction +
// deterministic final sum, one kernel, one launch.
// 8 blocks x 512 thr. Block g owns columns [g*256, g*256+256) (same grouping
// as the old k_colsum -> bit-identical float chain). Thread (cl = t&255,
// q = t>>8) sums slices [q*32, q*32+32) for all 30 bins of its column into
// u32 registers (exact integer partials; max bsum 32*13.4M < 2^32).
// q=1 half publishes via LDS; q=0 half adds, then replays the OLD per-column
// float arithmetic, the OLD 4-wave shfl reduce (same t<->col map), the OLD
// 8-term double finale. All loads wave-coalesced (64 consecutive cols/wave).
// ---------------------------------------------------------------------------
__global__ __launch_bounds__(512) void k_tail(
    const unsigned int* __restrict__ part,
    const float* __restrict__ acc_sum,
    float* __restrict__ blockPart, unsigned int* __restrict__ ctr,
    float* __restrict__ out)
{
    __shared__ unsigned int Lc[BINS * 256];   // 30720 B
    __shared__ unsigned int Ls[BINS * 256];   // 30720 B
    __shared__ float wave_sums[4];
    const int t  = threadIdx.x;
    const int cl = t & 255;
    const int q  = t >> 8;                    // 0 or 1: slice half
    const int colBase = blockIdx.x * 256;

    unsigned int cq[BINS], sq[BINS];
    #pragma unroll
    for (int b = 0; b < BINS; ++b) { cq[b] = 0u; sq[b] = 0u; }

    const unsigned int* Pp = part + (size_t)(q * 32) * (BINS * NCOLS)
                                  + colBase + cl;
    #pragma unroll 1
    for (int y = 0; y < 32; ++y) {
        #pragma unroll
        for (int b = 0; b < BINS; ++b) {
            const unsigned int v = Pp[(size_t)b * NCOLS];
            cq[b] += v >> CNT_SHIFT;
            sq[b] += v & SUM_MASK;
        }
        Pp += BINS * NCOLS;
    }

    if (q == 1) {
        #pragma unroll
        for (int b = 0; b < BINS; ++b) {
            Lc[b * 256 + cl] = cq[b];
            Ls[b * 256 + cl] = sq[b];
        }
    }
    __syncthreads();

    if (q == 0) {
        const int c = colBase + cl;
        float colsum = 0.0f;
        int n = 0;
        #pragma unroll
        for (int b = 0; b < BINS; ++b) {
            const unsigned int cu = cq[b] + Lc[b * 256 + cl];
            const unsigned int su = sq[b] + Ls[b * 256 + cl];
            const float cnt = (float)cu;                  // exact (<= 8192)
            if (cnt >= 1.0f) {
                n += 1;
                float acc_new = 0.75f * acc_sum[(size_t)b * NCOLS + c] + 0.25f * cnt;
                colsum += ((float)su * (1.0f / FIXED_SCALE)) / acc_new;
            }
        }
        colsum /= (float)((n > 1 ? n : 1) * NCOLS);

        #pragma unroll
        for (int off = 32; off > 0; off >>= 1)
            colsum += __shfl_down(colsum, off, 64);
        if ((t & 63) == 0) wave_sums[t >> 6] = colsum;
    }
    __syncthreads();

    if (t == 0) {
        const float s = wave_sums[0] + wave_sums[1] + wave_sums[2] + wave_sums[3];
        atomicExch(&blockPart[blockIdx.x], s);    // coherent publish
        __threadfence();
        if (atomicAdd(ctr, 1u) == 7u) {           // last block finishes
            __threadfence();
            double d = 0.0;
            #pragma unroll
            for (int i = 0; i < 8; ++i)
                d += (double)atomicAdd(&blockPart[i], 0.0f);  // coherent fetch
            out[0] = (float)d;
        }
    }
}

extern "C" void kernel_launch(void* const* d_in, const int* in_sizes, int n_in,
                              void* d_out, int out_size, void* d_ws, size_t ws_size,
                              hipStream_t stream)
{
    const float* preds   = (const float*)d_in[0];
    const int*   targets = (const int*)d_in[1];
    const float* acc_sum = (const float*)d_in[2];

    unsigned int* part = (unsigned int*)((char*)d_ws + WS_PART);
    float* blockPart   = (float*)((char*)d_ws + WS_BPART);
    unsigned int* ctr  = (unsigned int*)((char*)d_ws + WS_CTR);

    dim3 gA(NCOLS / COLS_PER_BLK, NROWS / ROWS_PER_BLK);   // (8, 64) = 512 blocks
    k_main<<<gA, 256, 0, stream>>>(preds, targets, part, ctr);

    k_tail<<<8, 512, 0, stream>>>(part, acc_sum, blockPart, ctr, (float*)d_out);
}

// Round 6
// 179.994 us; speedup vs baseline: 1.1237x; 1.1237x over previous
//
#include <hip/hip_runtime.h>

#define BINS  30
#define NROWS 8192
#define NCOLS 2048
#define COLS_PER_BLK 256                 // grid.x = 8
#define ROWS_PER_BLK 128                 // grid.y = 64
#define YSLICES 64
#define CELLS   (BINS * NCOLS)           // 61440

#define FIXED_SCALE 16384.0f             // 2^14 fixed point for bce
#define CNT_SHIFT   24                   // count bits [24:31], sum in [0:24)
#define SUM_MASK    ((1u << CNT_SHIFT) - 1)

// ws layout (bytes) — unchanged (no new workspace):
//   part : u32[YSLICES][BINS][NCOLS]   (15.7 MB)
//   blockPart: float[8]
//   ctr  : u32 (last-block-done counter)
#define WS_PART  0
#define WS_BPART (YSLICES * BINS * NCOLS * 4)
#define WS_CTR   (WS_BPART + 8 * 4)

// ---------------------------------------------------------------------------
// Kernel A (FROZEN since R3): direct column ownership.
// ~50 us wall invariant across 4 structures (atomics/staging/owner,
// float4/dword, 6-32 waves/CU) — unresolved; left untouched this round.
// ---------------------------------------------------------------------------
__global__ __launch_bounds__(256, 5) void k_main(
    const float* __restrict__ preds, const int* __restrict__ targets,
    unsigned int* __restrict__ part, unsigned int* __restrict__ ctr)
{
    __shared__ unsigned int H[BINS * COLS_PER_BLK];   // 30720 B
    const int t = threadIdx.x;
    if (blockIdx.x == 0 && blockIdx.y == 0 && t == 0) atomicExch(ctr, 0u);
    #pragma unroll
    for (int i = 0; i < BINS; ++i) H[i * COLS_PER_BLK + t] = 0u;
    __syncthreads();

    const int col = blockIdx.x * COLS_PER_BLK + t;
    const int r0  = blockIdx.y * ROWS_PER_BLK;
    const float* P = preds   + (size_t)r0 * NCOLS + col;
    const int*   T = targets + (size_t)r0 * NCOLS + col;

    // prologue: batch 0 (8 rows) in flight
    float pc[8]; int tc[8];
    #pragma unroll
    for (int r = 0; r < 8; ++r) { pc[r] = P[r * NCOLS]; tc[r] = T[r * NCOLS]; }

    #pragma unroll 1
    for (int batch = 0; batch < ROWS_PER_BLK / 8; ++batch) {
        float pn[8]; int tn[8];
        if (batch < ROWS_PER_BLK / 8 - 1) {
            P += 8 * NCOLS; T += 8 * NCOLS;
            #pragma unroll
            for (int r = 0; r < 8; ++r) { pn[r] = P[r * NCOLS]; tn[r] = T[r * NCOLS]; }
        }
        __builtin_amdgcn_sched_barrier(0);   // prefetch loads may not sink

        #pragma unroll
        for (int r = 0; r < 8; ++r) {
            float p  = pc[r];
            float pp = tc[r] ? -p : p;                    // p'
            float e  = __expf(-fabsf(pp));                // exp(-|p'|)
            float d  = 1.0f + e;
            float r1 = __builtin_amdgcn_rcpf(d);
            float g  = (pp >= 0.0f) ? r1 : e * r1;        // sigmoid(p')
            int   b  = (int)(g * 30.0f);
            b = b > (BINS - 1) ? (BINS - 1) : b;
            float bce = fmaxf(pp, 0.0f) + __logf(d);      // softplus(p')
            unsigned int pk = (1u << CNT_SHIFT)
                | (unsigned int)(bce * FIXED_SCALE + 0.5f);
            H[b * COLS_PER_BLK + t] += pk;                // exclusive, plain RMW
        }
        #pragma unroll
        for (int r = 0; r < 8; ++r) { pc[r] = pn[r]; tc[r] = tn[r]; }
    }
    __syncthreads();

    // flush: straight copy, coalesced
    const size_t outBase = (size_t)blockIdx.y * BINS * NCOLS
                         + (size_t)blockIdx.x * COLS_PER_BLK;
    for (int i = t; i < BINS * COLS_PER_BLK; i += 256)
        part[outBase + (size_t)(i >> 8) * NCOLS + (i & 255)] = H[i];
}

// ---------------------------------------------------------------------------
// Kernel B (R5): parallel y-slice reduction, IN-PLACE into part.
// R4 post-mortem: 8-block fused tail = 53 us at 0.6% occupancy. Fix =
// parallelism. 960 blocks x 256 thr; thread (chunk = gid/CELLS in [0,4),
// cell = gid%CELLS) sums slices [16*chunk, 16*chunk+16) of its cell:
// 16 independent coalesced loads, ~15 waves/CU chip-wide.
// In-place: cnt-partial -> part[16*chunk][cell], sum-partial ->
// part[16*chunk+1][cell]. Both addresses are in THIS thread's private
// 16-slice read set and in no other thread's -> race-free, zero extra ws.
// Overflow: cnt <= 16*128 = 2048; sum <= 16*13.4M = 225M < 2^32. Exact.
// ---------------------------------------------------------------------------
__global__ __launch_bounds__(256) void k_reduce16(
    unsigned int* __restrict__ part)
{
    const int gid   = blockIdx.x * 256 + threadIdx.x;   // 0 .. 245759
    const int chunk = gid / CELLS;                      // 0..3
    const int cell  = gid % CELLS;
    unsigned int* Pp = part + (size_t)(chunk * 16) * CELLS + cell;

    unsigned int c = 0u, s = 0u;
    #pragma unroll
    for (int y = 0; y < 16; ++y) {
        const unsigned int v = Pp[(size_t)y * CELLS];
        c += v >> CNT_SHIFT;
        s += v & SUM_MASK;
    }
    Pp[0]     = c;      // slice 16*chunk   : cnt partial
    Pp[CELLS] = s;      // slice 16*chunk+1 : sum partial
}

// ---------------------------------------------------------------------------
// Kernel C (R5): per-column contraction + deterministic finale.
// EXACT replica of R3/R4's float chain (same thread<->column map, same
// ordered b-loop, same 64-wide shfl, same wave_sums[4], same 8-term double
// finale) -> bit-identical output. Only the loads differ: 4 cnt + 4 sum
// partials (exact u32 adds -> same totals) + 1 acc_sum per bin, all
// coalesced and L2-warm (2.2 MB), 270 independent loads per thread.
// ---------------------------------------------------------------------------
__global__ __launch_bounds__(256) void k_tail(
    const unsigned int* __restrict__ part,
    const float* __restrict__ acc_sum,
    float* __restrict__ blockPart, unsigned int* __restrict__ ctr,
    float* __restrict__ out)
{
    __shared__ float wave_sums[4];
    const int t = threadIdx.x;
    const int c = blockIdx.x * 256 + t;

    float colsum = 0.0f;
    int n = 0;
    #pragma unroll
    for (int b = 0; b < BINS; ++b) {
        const int cell = b * NCOLS + c;
        unsigned int cu = part[(size_t) 0 * CELLS + cell]
                        + part[(size_t)16 * CELLS + cell]
                        + part[(size_t)32 * CELLS + cell]
                        + part[(size_t)48 * CELLS + cell];
        unsigned int su = part[(size_t) 1 * CELLS + cell]
                        + part[(size_t)17 * CELLS + cell]
                        + part[(size_t)33 * CELLS + cell]
                        + part[(size_t)49 * CELLS + cell];
        const float cnt = (float)cu;                  // exact (<= 8192)
        if (cnt >= 1.0f) {
            n += 1;
            float acc_new = 0.75f * acc_sum[cell] + 0.25f * cnt;
            colsum += ((float)su * (1.0f / FIXED_SCALE)) / acc_new;
        }
    }
    colsum /= (float)((n > 1 ? n : 1) * NCOLS);

    #pragma unroll
    for (int off = 32; off > 0; off >>= 1)
        colsum += __shfl_down(colsum, off, 64);
    if ((t & 63) == 0) wave_sums[t >> 6] = colsum;
    __syncthreads();

    if (t == 0) {
        const float s = wave_sums[0] + wave_sums[1] + wave_sums[2] + wave_sums[3];
        atomicExch(&blockPart[blockIdx.x], s);    // coherent publish
        __threadfence();
        if (atomicAdd(ctr, 1u) == 7u) {           // last block finishes
            __threadfence();
            double d = 0.0;
            #pragma unroll
            for (int i = 0; i < 8; ++i)
                d += (double)atomicAdd(&blockPart[i], 0.0f);  // coherent fetch
            out[0] = (float)d;
        }
    }
}

extern "C" void kernel_launch(void* const* d_in, const int* in_sizes, int n_in,
                              void* d_out, int out_size, void* d_ws, size_t ws_size,
                              hipStream_t stream)
{
    const float* preds   = (const float*)d_in[0];
    const int*   targets = (const int*)d_in[1];
    const float* acc_sum = (const float*)d_in[2];

    unsigned int* part = (unsigned int*)((char*)d_ws + WS_PART);
    float* blockPart   = (float*)((char*)d_ws + WS_BPART);
    unsigned int* ctr  = (unsigned int*)((char*)d_ws + WS_CTR);

    dim3 gA(NCOLS / COLS_PER_BLK, NROWS / ROWS_PER_BLK);   // (8, 64) = 512 blocks
    k_main<<<gA, 256, 0, stream>>>(preds, targets, part, ctr);

    k_reduce16<<<(4 * CELLS) / 256, 256, 0, stream>>>(part);   // 960 blocks

    k_tail<<<NCOLS / 256, 256, 0, stream>>>(part, acc_sum, blockPart, ctr,
                                            (float*)d_out);
}